// Round 2
// baseline (374.569 us; speedup 1.0000x reference)
//
#include <hip/hip_runtime.h>

#define NPOS 32768   // 32 * 32 * 32 positions
#define DDIM 256
#define KCODES 1024
#define TM 64        // positions per block
#define TN 256       // codes per ct-tile
#define BK 16        // d-chunk
#define ASTR 68      // As row stride (floats)
#define BSTR 284     // Bs row stride (floats), holds 256 cols + 4-float skew per 32 cols
#define NCT (KCODES / TN)   // 4

// ---- fp32 ops with anti-contraction barriers (replicate numpy rounding) ----
__device__ __forceinline__ float sqr_rn(float x) {
    float r = x * x;
    asm volatile("" : "+v"(r));
    return r;
}
__device__ __forceinline__ float add_rn(float a, float b) {
    float r = a + b;
    asm volatile("" : "+v"(r));
    return r;
}

// numpy pairwise_sum of 128 squared elements (strided): r[0..7] sequential
// accumulators, combined ((r0+r1)+(r2+r3))+((r4+r5)+(r6+r7)).
template <int S>
__device__ __forceinline__ float np_sumsq128(const float* __restrict__ p) {
    float r[8];
#pragma unroll
    for (int j = 0; j < 8; ++j) r[j] = sqr_rn(p[j * S]);
#pragma unroll
    for (int i = 8; i < 128; i += 8)
#pragma unroll
        for (int j = 0; j < 8; ++j) r[j] = add_rn(r[j], sqr_rn(p[(i + j) * S]));
    return add_rn(add_rn(add_rn(r[0], r[1]), add_rn(r[2], r[3])),
                  add_rn(add_rn(r[4], r[5]), add_rn(r[6], r[7])));
}

// zsq[p] = numpy-pairwise sum of squares over D for position p (NCHW layout)
__global__ __launch_bounds__(256) void zsq_np(const float* __restrict__ z,
                                              float* __restrict__ zsq) {
    int p = blockIdx.x * 256 + threadIdx.x;
    const float* base = z + (p >> 10) * (DDIM * 1024) + (p & 1023);
    zsq[p] = add_rn(np_sumsq128<1024>(base), np_sumsq128<1024>(base + 128 * 1024));
}

// wsq[k] = numpy-pairwise sum of squares of codebook row k
__global__ __launch_bounds__(256) void wsq_np(const float* __restrict__ W,
                                              float* __restrict__ wsq) {
    int k = blockIdx.x * 256 + threadIdx.x;
    const float* row = W + k * DDIM;
    wsq[k] = add_rn(np_sumsq128<1>(row), np_sumsq128<1>(row + 128));
}

// Fused SGEMM + fp32 score + argmin (first-index tie-break).
// Block: 256 threads = 8 rowgroups (8 rows each) x 32 colgroups (8 cols each).
// score = fl(fl(zsq - 2*dot) + wsq), dot accumulated with sequential fmaf over
// d ascending (matches BLAS sgemm microkernel accumulation order).
__global__ __launch_bounds__(256, 2) void vq_main(const float* __restrict__ z,
                                                  const float* __restrict__ W,
                                                  const float* __restrict__ zsq,
                                                  const float* __restrict__ wsq,
                                                  int* __restrict__ out) {
    __shared__ float  As[BK * ASTR];
    __shared__ float  Bs[BK * BSTR];
    __shared__ float2 red[TM * 32];

    const int t  = threadIdx.x;
    const int cg = t & 31;   // colgroup: 8 codes each
    const int rg = t >> 5;   // rowgroup: 8 rows each
    const int m0 = blockIdx.x * TM;
    const float* zb = z + (m0 >> 10) * (DDIM * 1024) + (m0 & 1023);

    // staging decompositions
    const int mst  = t & 63;          // A: position in tile
    const int dst4 = (t >> 6) * 4;    // A: 4 d-rows per thread
    const int bn0  = t >> 4;          // B: code base (+16*j)
    const int bdl  = t & 15;          // B: d within chunk
    const int bb   = cg * 8 + (cg >> 2) * 4;   // skewed read base (conflict-free)

    float zq[8];
#pragma unroll
    for (int r = 0; r < 8; ++r) zq[r] = zsq[m0 + rg * 8 + r];

    float bsc[8];
    int   bix[8];
#pragma unroll
    for (int r = 0; r < 8; ++r) { bsc[r] = 1e30f; bix[r] = 0; }

    for (int ct = 0; ct < NCT; ++ct) {
        float acc[8][8];
#pragma unroll
        for (int r = 0; r < 8; ++r)
#pragma unroll
            for (int c = 0; c < 8; ++c) acc[r][c] = 0.f;

        const float* wb = W + ct * TN * DDIM;

        for (int kk = 0; kk < DDIM / BK; ++kk) {
            const int dg0 = kk * BK;
            // stage A: [d][m], coalesced (64 consecutive hw per d-row)
#pragma unroll
            for (int j = 0; j < 4; ++j) {
                int dl = dst4 + j;
                As[dl * ASTR + mst] = zb[(dg0 + dl) * 1024 + mst];
            }
            // stage B: [d][skewed n], 64B-coalesced global reads per code row
#pragma unroll
            for (int j = 0; j < 16; ++j) {
                int n = bn0 + 16 * j;
                Bs[bdl * BSTR + n + (n >> 5) * 4] = wb[n * DDIM + dg0 + bdl];
            }
            __syncthreads();
#pragma unroll
            for (int d = 0; d < BK; ++d) {
                const float4 a0 = *(const float4*)&As[d * ASTR + rg * 8];
                const float4 a1 = *(const float4*)&As[d * ASTR + rg * 8 + 4];
                const float4 b0 = *(const float4*)&Bs[d * BSTR + bb];
                const float4 b1 = *(const float4*)&Bs[d * BSTR + bb + 4];
                const float av[8] = {a0.x, a0.y, a0.z, a0.w, a1.x, a1.y, a1.z, a1.w};
                const float bv[8] = {b0.x, b0.y, b0.z, b0.w, b1.x, b1.y, b1.z, b1.w};
#pragma unroll
                for (int r = 0; r < 8; ++r)
#pragma unroll
                    for (int c = 0; c < 8; ++c)
                        acc[r][c] = fmaf(av[r], bv[c], acc[r][c]);
            }
            __syncthreads();
        }
        // epilogue: fp32 score exactly as numpy: fl(fl(zsq - 2*M) + wsq)
#pragma unroll
        for (int c = 0; c < 8; ++c) {
            const int code = ct * TN + cg * 8 + c;
            const float wq = wsq[code];
#pragma unroll
            for (int r = 0; r < 8; ++r) {
                float s = add_rn(fmaf(-2.0f, acc[r][c], zq[r]), wq);
                // codes visited in ascending order per thread: strict < keeps
                // the first (lowest) index on exact ties, matching np.argmin
                if (s < bsc[r]) { bsc[r] = s; bix[r] = code; }
            }
        }
    }

    // cross-thread lexicographic (score, idx) argmin per row
#pragma unroll
    for (int r = 0; r < 8; ++r)
        red[(rg * 8 + r) * 32 + cg] = make_float2(bsc[r], __int_as_float(bix[r]));
    __syncthreads();
    if (t < TM) {
        float best = 1e30f;
        int   bidx = 0x7fffffff;
        const float2* rr = &red[t * 32];
        for (int e = 0; e < 32; ++e) {
            float s = rr[e].x;
            int   i = __float_as_int(rr[e].y);
            if (s < best || (s == best && i < bidx)) { best = s; bidx = i; }
        }
        out[m0 + t] = bidx;
    }
}

extern "C" void kernel_launch(void* const* d_in, const int* in_sizes, int n_in,
                              void* d_out, int out_size, void* d_ws, size_t ws_size,
                              hipStream_t stream) {
    const float* z = (const float*)d_in[0];   // [32, 256, 32, 32] NCHW
    const float* W = (const float*)d_in[1];   // [1024, 256]
    int* out = (int*)d_out;                   // [32768] int32 indices

    float* zsq = (float*)d_ws;                         // 128 KB
    float* wsq = (float*)((char*)d_ws + NPOS * 4);     // 4 KB

    zsq_np<<<NPOS / 256, 256, 0, stream>>>(z, zsq);
    wsq_np<<<KCODES / 256, 256, 0, stream>>>(W, wsq);
    vq_main<<<NPOS / TM, 256, 0, stream>>>(z, W, zsq, wsq, out);
}

// Round 3
// 368.397 us; speedup vs baseline: 1.0168x; 1.0168x over previous
//
#include <hip/hip_runtime.h>

#define NPOS 32768   // 32 * 32 * 32 positions
#define DDIM 256
#define KCODES 1024
#define TM 64        // positions per block
#define BK 16        // d-chunk
#define ASTR 68      // As row stride (floats)
#define BSTR 20      // Bs per-code row: 16 d-floats + 4 pad (80 B, 16B-aligned, bank-spread)

// ---- fp32 ops with anti-contraction barriers (replicate numpy rounding) ----
__device__ __forceinline__ float sqr_rn(float x) {
    float r = x * x;
    asm volatile("" : "+v"(r));
    return r;
}
__device__ __forceinline__ float add_rn(float a, float b) {
    float r = a + b;
    asm volatile("" : "+v"(r));
    return r;
}

// numpy pairwise_sum of 128 squared elements (strided): 8 sequential
// accumulators combined ((r0+r1)+(r2+r3))+((r4+r5)+(r6+r7)).
template <int S>
__device__ __forceinline__ float np_sumsq128(const float* __restrict__ p) {
    float r[8];
#pragma unroll
    for (int j = 0; j < 8; ++j) r[j] = sqr_rn(p[j * S]);
#pragma unroll
    for (int i = 8; i < 128; i += 8)
#pragma unroll
        for (int j = 0; j < 8; ++j) r[j] = add_rn(r[j], sqr_rn(p[(i + j) * S]));
    return add_rn(add_rn(add_rn(r[0], r[1]), add_rn(r[2], r[3])),
                  add_rn(add_rn(r[4], r[5]), add_rn(r[6], r[7])));
}

// zsq, d-split 2-way: 256 blocks, fully coalesced, half-chains joined via LDS.
__global__ __launch_bounds__(256) void zsq2(const float* __restrict__ z,
                                            float* __restrict__ zsq) {
    __shared__ float tmp[128];
    const int t = threadIdx.x;
    const int p = blockIdx.x * 128 + (t & 127);
    const int h = t >> 7;
    const float* base = z + (p >> 10) * (DDIM * 1024) + (p & 1023) + h * (128 * 1024);
    float v = np_sumsq128<1024>(base);
    if (h) tmp[t & 127] = v;
    __syncthreads();
    if (!h) zsq[p] = add_rn(v, tmp[t]);   // add_rn(half0, half1): numpy order
}

// wsq via 16-lane butterfly reproducing numpy's exact pairwise tree.
// Lane j owns chain j: elements (j&7) + 128*(j>>3) + 8i, i=0..15 (sequential).
// xor1/xor2/xor4 rebuild ((r0+r1)+(r2+r3))+((r4+r5)+(r6+r7)); xor8 joins halves.
// IEEE add is commutative, so per-lane operand order is bit-identical.
__global__ __launch_bounds__(256) void wsq16(const float* __restrict__ W,
                                             float* __restrict__ wsq) {
    const int t   = threadIdx.x;
    const int row = blockIdx.x * 16 + (t >> 4);
    const int j   = t & 15;
    const float* base = W + row * DDIM + (j & 7) + (j >> 3) * 128;
    float r = sqr_rn(base[0]);
#pragma unroll
    for (int i = 1; i < 16; ++i) r = add_rn(r, sqr_rn(base[i * 8]));
#pragma unroll
    for (int m = 1; m <= 8; m <<= 1) r = add_rn(r, __shfl_xor(r, m));
    if (j == 0) wsq[row] = r;
}

// Fused SGEMM + fp32 score + per-half argmin.
// Block: 64 positions x 512 codes (half = blockIdx&1), 2 ct-tiles of 256 codes.
// Thread (cg = t&31, rg = t>>5): rows rg*8..+7, codes cg+32c (c=0..7) per tile.
// M chain: sequential fmaf over d = 0..255 ascending (bit-identical to round 2).
__global__ __launch_bounds__(256, 3) void vq_half(const float* __restrict__ z,
                                                  const float* __restrict__ W,
                                                  const float* __restrict__ zsq,
                                                  const float* __restrict__ wsq,
                                                  unsigned long long* __restrict__ cand) {
    __shared__ float As[BK * ASTR];       //  4.4 KB  [d][m]
    __shared__ float Bs[256 * BSTR];      // 20.5 KB  [n_local][d-quad floats + pad]

    const int t    = threadIdx.x;
    const int cg   = t & 31;
    const int rg   = t >> 5;
    const int half = blockIdx.x & 1;
    const int m0   = (blockIdx.x >> 1) * TM;
    const float* zb = z + (m0 >> 10) * (DDIM * 1024) + (m0 & 1023);

    // staging decompositions
    const int ad  = t >> 4;        // A: d-row 0..15
    const int am4 = (t & 15) * 4;  // A: m base (float4 over positions)
    const int bn  = t >> 2;        // B: code row base (+64q)
    const int bq  = t & 3;         // B: d-quad (float4 over d)

    float zq[8];
#pragma unroll
    for (int r = 0; r < 8; ++r) zq[r] = zsq[m0 + rg * 8 + r];

    float bsc[8];
    int   bix[8];
#pragma unroll
    for (int r = 0; r < 8; ++r) { bsc[r] = 1e30f; bix[r] = 0; }

#pragma unroll 1
    for (int ct = half * 2; ct < half * 2 + 2; ++ct) {
        float acc[8][8];
#pragma unroll
        for (int r = 0; r < 8; ++r)
#pragma unroll
            for (int c = 0; c < 8; ++c) acc[r][c] = 0.f;

        const float* wb = W + ct * 256 * DDIM;

#pragma unroll 1
        for (int kk = 0; kk < DDIM / BK; ++kk) {
            const int dg0 = kk * BK;
            // stage A: one float4 over positions per thread (coalesced 256B/16 lanes)
            *(float4*)&As[ad * ASTR + am4] = *(const float4*)&zb[(dg0 + ad) * 1024 + am4];
            // stage B: four float4 over d per thread (64B contiguous per code)
#pragma unroll
            for (int q = 0; q < 4; ++q) {
                const int n = bn + 64 * q;
                *(float4*)&Bs[n * BSTR + bq * 4] = *(const float4*)&wb[n * DDIM + dg0 + bq * 4];
            }
            __syncthreads();
#pragma unroll
            for (int dq = 0; dq < 4; ++dq) {
                float a[4][8];
#pragma unroll
                for (int i = 0; i < 4; ++i) {
                    const float4 x = *(const float4*)&As[(dq * 4 + i) * ASTR + rg * 8];
                    const float4 y = *(const float4*)&As[(dq * 4 + i) * ASTR + rg * 8 + 4];
                    a[i][0] = x.x; a[i][1] = x.y; a[i][2] = x.z; a[i][3] = x.w;
                    a[i][4] = y.x; a[i][5] = y.y; a[i][6] = y.z; a[i][7] = y.w;
                }
#pragma unroll
                for (int c = 0; c < 8; ++c) {
                    const float4 b = *(const float4*)&Bs[(cg + 32 * c) * BSTR + dq * 4];
#pragma unroll
                    for (int r = 0; r < 8; ++r) {
                        float t0 = acc[r][c];
                        t0 = fmaf(a[0][r], b.x, t0);   // d ascending: exact chain order
                        t0 = fmaf(a[1][r], b.y, t0);
                        t0 = fmaf(a[2][r], b.z, t0);
                        t0 = fmaf(a[3][r], b.w, t0);
                        acc[r][c] = t0;
                    }
                }
            }
            __syncthreads();
        }
        // epilogue: numpy score fl(fl(zsq - 2M) + wsq); codes ascending per thread,
        // strict < keeps first (lowest) index on exact ties.
#pragma unroll
        for (int c = 0; c < 8; ++c) {
            const int code = ct * 256 + cg + 32 * c;
            const float wq = wsq[code];
#pragma unroll
            for (int r = 0; r < 8; ++r) {
                float s = add_rn(fmaf(-2.0f, acc[r][c], zq[r]), wq);
                if (s < bsc[r]) { bsc[r] = s; bix[r] = code; }
            }
        }
    }

    // cross-lane argmin: packed (score_bits<<32)|idx, u64 min = lexicographic
    // (scores are ~255 > 0, so float bits are monotone).
#pragma unroll
    for (int r = 0; r < 8; ++r) {
        unsigned long long v =
            ((unsigned long long)__float_as_uint(bsc[r]) << 32) | (unsigned)bix[r];
#pragma unroll
        for (int m = 1; m <= 16; m <<= 1) {
            unsigned long long o = __shfl_xor(v, m);
            if (o < v) v = o;
        }
        if (cg == 0) cand[half * NPOS + m0 + rg * 8 + r] = v;
    }
}

// final merge of the two code-halves per position
__global__ __launch_bounds__(256) void vq_merge(const unsigned long long* __restrict__ cand,
                                                int* __restrict__ out) {
    const int p = blockIdx.x * 256 + threadIdx.x;
    const unsigned long long a = cand[p];
    const unsigned long long b = cand[NPOS + p];
    const unsigned long long m = (b < a) ? b : a;
    out[p] = (int)(unsigned)(m & 0xffffffffULL);
}

extern "C" void kernel_launch(void* const* d_in, const int* in_sizes, int n_in,
                              void* d_out, int out_size, void* d_ws, size_t ws_size,
                              hipStream_t stream) {
    const float* z = (const float*)d_in[0];   // [32, 256, 32, 32] NCHW
    const float* W = (const float*)d_in[1];   // [1024, 256]
    int* out = (int*)d_out;                   // [32768] int32 indices

    float* zsq = (float*)d_ws;                                        // 128 KB
    float* wsq = (float*)((char*)d_ws + NPOS * 4);                    //   4 KB
    unsigned long long* cand =
        (unsigned long long*)((char*)d_ws + NPOS * 4 + KCODES * 4);   // 512 KB

    zsq2<<<NPOS / 128, 256, 0, stream>>>(z, zsq);
    wsq16<<<KCODES / 16, 256, 0, stream>>>(W, wsq);
    vq_half<<<(NPOS / TM) * 2, 256, 0, stream>>>(z, W, zsq, wsq, cand);
    vq_merge<<<NPOS / 256, 256, 0, stream>>>(cand, out);
}

// Round 4
// 203.247 us; speedup vs baseline: 1.8429x; 1.8126x over previous
//
#include <hip/hip_runtime.h>

#define NPOS 32768   // 32 * 32 * 32 positions
#define DDIM 256
#define KCODES 1024

typedef __attribute__((ext_vector_type(8))) short bf16x8;
typedef __attribute__((ext_vector_type(4))) float f32x4;
typedef unsigned long long u64;

// ---- fp32 ops with anti-contraction barriers (replicate numpy rounding) ----
__device__ __forceinline__ float sqr_rn(float x) {
    float r = x * x;
    asm volatile("" : "+v"(r));
    return r;
}
__device__ __forceinline__ float add_rn(float a, float b) {
    float r = a + b;
    asm volatile("" : "+v"(r));
    return r;
}

// numpy pairwise_sum of 128 squared elements (strided): 8 sequential
// accumulators combined ((r0+r1)+(r2+r3))+((r4+r5)+(r6+r7)).
template <int S>
__device__ __forceinline__ float np_sumsq128(const float* __restrict__ p) {
    float r[8];
#pragma unroll
    for (int j = 0; j < 8; ++j) r[j] = sqr_rn(p[j * S]);
#pragma unroll
    for (int i = 8; i < 128; i += 8)
#pragma unroll
        for (int j = 0; j < 8; ++j) r[j] = add_rn(r[j], sqr_rn(p[(i + j) * S]));
    return add_rn(add_rn(add_rn(r[0], r[1]), add_rn(r[2], r[3])),
                  add_rn(add_rn(r[4], r[5]), add_rn(r[6], r[7])));
}

// zsq, d-split 2-way (verified bit-exact in rounds 2-3)
__global__ __launch_bounds__(256) void zsq2(const float* __restrict__ z,
                                            float* __restrict__ zsq) {
    __shared__ float tmp[128];
    const int t = threadIdx.x;
    const int p = blockIdx.x * 128 + (t & 127);
    const int h = t >> 7;
    const float* base = z + (p >> 10) * (DDIM * 1024) + (p & 1023) + h * (128 * 1024);
    float v = np_sumsq128<1024>(base);
    if (h) tmp[t & 127] = v;
    __syncthreads();
    if (!h) zsq[p] = add_rn(v, tmp[t]);
}

// wsq via 16-lane butterfly, numpy-exact pairwise tree (verified round 3)
__global__ __launch_bounds__(256) void wsq16(const float* __restrict__ W,
                                             float* __restrict__ wsq) {
    const int t   = threadIdx.x;
    const int row = blockIdx.x * 16 + (t >> 4);
    const int j   = t & 15;
    const float* base = W + row * DDIM + (j & 7) + (j >> 3) * 128;
    float r = sqr_rn(base[0]);
#pragma unroll
    for (int i = 1; i < 16; ++i) r = add_rn(r, sqr_rn(base[i * 8]));
#pragma unroll
    for (int m = 1; m <= 8; m <<= 1) r = add_rn(r, __shfl_xor(r, m));
    if (j == 0) wsq[row] = r;
}

// fp32 -> bf16 round-to-nearest-even
__device__ __forceinline__ unsigned short f2bf(float x) {
    unsigned u = __float_as_uint(x);
    return (unsigned short)((u + 0x7fffu + ((u >> 16) & 1u)) >> 16);
}

// monotone pack: float score -> order-preserving u32, | code in low bits
__device__ __forceinline__ u64 packm(float s, int code) {
    unsigned b = __float_as_uint(s);
    unsigned mm = ((unsigned)((int)b >> 31)) | 0x80000000u;
    return ((u64)(b ^ mm) << 32) | (unsigned)code;
}

// ---------------- bf16 MFMA GEMM + per-block top-2 filter ----------------
// Grid 1024: mblk = bid>>2 (128 positions), nblk = bid&3 (256 codes).
// Block 256 thr = 4 waves; wave-tile 64 M x 128 N of mfma_f32_16x16x32_bf16.
// A-frag: A[m=lane&15][k=q*8+j], B-frag: B[n=lane&15][k=q*8+j],
// C/D: col=lane&15, row=q*4+reg (m89-verified).
__global__ __launch_bounds__(256) __attribute__((amdgpu_waves_per_eu(2, 2)))
void gemm_top2(const float* __restrict__ z, const float* __restrict__ W,
               const float* __restrict__ wsq, u64* __restrict__ cand) {
    __shared__ u64 redU[128 * 32];            // 32 KB; staging aliased below
    short* Abuf = (short*)redU;               // [128 m][32 k] bf16
    short* Bbuf = Abuf + 128 * 32;            // [256 n][32 k] bf16

    const int t    = threadIdx.x;
    const int lane = t & 63;
    const int w    = t >> 6;
    const int ln   = lane & 15;
    const int q    = lane >> 4;
    const int mw   = (w & 1) * 64;
    const int nw   = (w >> 1) * 128;
    const int mblk = blockIdx.x >> 2;
    const int nblk = blockIdx.x & 3;
    const int m0   = mblk * 128;
    const int n0   = nblk * 256;
    const float* zb = z + (m0 >> 10) * (DDIM * 1024) + (m0 & 1023);

    const int kq = t & 3;    // 8-k group
    const int sr = t >> 2;   // 0..63

    f32x4 acc[4][8];
#pragma unroll
    for (int a = 0; a < 4; ++a)
#pragma unroll
        for (int b = 0; b < 8; ++b) acc[a][b] = (f32x4)(0.f);

#pragma unroll 1
    for (int kk = 0; kk < 8; ++kk) {
        const int k0 = kk * 32;
        // stage A: 2 rows per thread, 8 k each (scalar fp32 -> bf16)
#pragma unroll
        for (int h = 0; h < 2; ++h) {
            const int m = sr + h * 64;
            bf16x8 v;
#pragma unroll
            for (int i = 0; i < 8; ++i)
                v[i] = (short)f2bf(zb[(k0 + kq * 8 + i) * 1024 + m]);
            *(bf16x8*)&Abuf[m * 32 + kq * 8] = v;
        }
        // stage B: 4 rows per thread, 8 k each (2x float4 -> bf16)
#pragma unroll
        for (int j = 0; j < 4; ++j) {
            const int n = sr + 64 * j;
            const float4 f0 = *(const float4*)&W[(n0 + n) * DDIM + k0 + kq * 8];
            const float4 f1 = *(const float4*)&W[(n0 + n) * DDIM + k0 + kq * 8 + 4];
            bf16x8 v;
            v[0] = (short)f2bf(f0.x); v[1] = (short)f2bf(f0.y);
            v[2] = (short)f2bf(f0.z); v[3] = (short)f2bf(f0.w);
            v[4] = (short)f2bf(f1.x); v[5] = (short)f2bf(f1.y);
            v[6] = (short)f2bf(f1.z); v[7] = (short)f2bf(f1.w);
            *(bf16x8*)&Bbuf[n * 32 + kq * 8] = v;
        }
        __syncthreads();
        bf16x8 bfr[8];
#pragma unroll
        for (int nf = 0; nf < 8; ++nf)
            bfr[nf] = *(const bf16x8*)&Bbuf[(nw + nf * 16 + ln) * 32 + q * 8];
#pragma unroll
        for (int mf = 0; mf < 4; ++mf) {
            const bf16x8 afr = *(const bf16x8*)&Abuf[(mw + mf * 16 + ln) * 32 + q * 8];
#pragma unroll
            for (int nf = 0; nf < 8; ++nf)
                acc[mf][nf] = __builtin_amdgcn_mfma_f32_16x16x32_bf16(
                    afr, bfr[nf], acc[mf][nf], 0, 0, 0);
        }
        __syncthreads();
    }

    // ---- epilogue: approx score = wsq - 2*acc, per-row top-2 ----
    float wq[8];
#pragma unroll
    for (int nf = 0; nf < 8; ++nf) wq[nf] = wsq[n0 + nw + nf * 16 + ln];

#pragma unroll
    for (int mf = 0; mf < 4; ++mf) {
#pragma unroll
        for (int reg = 0; reg < 4; ++reg) {
            const int row = mw + mf * 16 + q * 4 + reg;
            float s0 = 1e30f, s1 = 1e30f;
            int   i0 = 0,     i1 = 0;
#pragma unroll
            for (int nf = 0; nf < 8; ++nf) {
                const float s  = fmaf(-2.f, acc[mf][nf][reg], wq[nf]);
                const int   cc = n0 + nw + nf * 16 + ln;
                if (s < s0)      { s1 = s0; i1 = i0; s0 = s; i0 = cc; }
                else if (s < s1) { s1 = s; i1 = cc; }
            }
            u64 p0 = packm(s0, i0), p1 = packm(s1, i1);
            // xor-1 merge: partner lane has same rows, different cols
            const u64 o0 = __shfl_xor(p0, 1);
            const u64 o1 = __shfl_xor(p1, 1);
            const u64 c0 = (p0 < o0) ? p0 : o0;
            const u64 hi = (p0 < o0) ? o0 : p0;
            const u64 lo = (p1 < o1) ? p1 : o1;
            const u64 c1 = (hi < lo) ? hi : lo;
            if ((ln & 1) == 0) {
                u64* slot = &redU[row * 32 + (w >> 1) * 16 + (ln >> 1) * 2];
                slot[0] = c0;
                slot[1] = c1;
            }
        }
    }
    __syncthreads();

    // scan: 2 threads per row, 16 entries each -> top-2
    {
        const int r2 = t >> 1, half = t & 1;
        u64 c0 = ~0ull, c1 = ~0ull;
#pragma unroll
        for (int j = 0; j < 16; ++j) {
            const u64 v = redU[r2 * 32 + half * 16 + j];
            if (v < c0)      { c1 = c0; c0 = v; }
            else if (v < c1) { c1 = v; }
        }
        __syncthreads();
        redU[r2 * 4 + half * 2]     = c0;
        redU[r2 * 4 + half * 2 + 1] = c1;
    }
    __syncthreads();
    if (t < 128) {
        const u64 a = redU[t * 4], b = redU[t * 4 + 1];
        const u64 c = redU[t * 4 + 2], d = redU[t * 4 + 3];
        const u64 m1 = (a < c) ? a : c;
        const u64 hi = (a < c) ? c : a;
        const u64 lo = (b < d) ? b : d;
        const u64 m2 = (hi < lo) ? hi : lo;
        u64* o = &cand[(u64)(m0 + t) * 8 + nblk * 2];
        o[0] = m1;
        o[1] = m2;
    }
}

// ---------------- exact numpy-bit rescore of 8 candidates/position ----------------
__global__ __launch_bounds__(256) void rescore(const float* __restrict__ z,
                                               const float* __restrict__ W,
                                               const float* __restrict__ zsq,
                                               const float* __restrict__ wsq,
                                               const u64* __restrict__ cand,
                                               int* __restrict__ out) {
    const int idx  = blockIdx.x * 256 + threadIdx.x;
    const int p    = idx >> 3;
    const int slot = idx & 7;
    const int code = (int)(unsigned)(cand[(u64)p * 8 + slot] & 0xffffffffull);
    const float* zr = z + (p >> 10) * (DDIM * 1024) + (p & 1023);
    const float* wr = W + code * DDIM;
    // sequential fma chain over d ascending — bit-identical to BLAS sgemm elem
    float M = 0.f;
#pragma unroll 8
    for (int d = 0; d < DDIM; ++d) M = fmaf(zr[d * 1024], wr[d], M);
    const float s = add_rn(fmaf(-2.f, M, zsq[p]), wsq[code]);
    // exact scores are ~chi2_256 > 0: plain bit-pack is monotone
    u64 v = ((u64)__float_as_uint(s) << 32) | (unsigned)code;
#pragma unroll
    for (int m = 1; m <= 4; m <<= 1) {
        const u64 o = __shfl_xor(v, m);
        if (o < v) v = o;
    }
    if (slot == 0) out[p] = (int)(unsigned)(v & 0xffffffffull);
}

extern "C" void kernel_launch(void* const* d_in, const int* in_sizes, int n_in,
                              void* d_out, int out_size, void* d_ws, size_t ws_size,
                              hipStream_t stream) {
    const float* z = (const float*)d_in[0];   // [32, 256, 32, 32] NCHW
    const float* W = (const float*)d_in[1];   // [1024, 256]
    int* out = (int*)d_out;                   // [32768] int32 indices

    float* zsq = (float*)d_ws;                                   // 128 KB
    float* wsq = (float*)((char*)d_ws + NPOS * 4);               //   4 KB
    u64*   cand = (u64*)((char*)d_ws + NPOS * 4 + KCODES * 4);   //   2 MB

    zsq2<<<NPOS / 128, 256, 0, stream>>>(z, zsq);
    wsq16<<<KCODES / 16, 256, 0, stream>>>(W, wsq);
    gemm_top2<<<(NPOS / 128) * 4, 256, 0, stream>>>(z, W, wsq, cand);
    rescore<<<NPOS * 8 / 256, 256, 0, stream>>>(z, W, zsq, wsq, cand, out);
}

// Round 5
// 163.372 us; speedup vs baseline: 2.2927x; 1.2441x over previous
//
#include <hip/hip_runtime.h>

#define NPOS 32768   // 32 * 32 * 32 positions
#define DDIM 256
#define KCODES 1024

typedef __attribute__((ext_vector_type(8))) short bf16x8;
typedef __attribute__((ext_vector_type(4))) float f32x4;
typedef unsigned long long u64;

// ---- fp32 ops with anti-contraction barriers (replicate numpy rounding) ----
__device__ __forceinline__ float sqr_rn(float x) {
    float r = x * x;
    asm volatile("" : "+v"(r));
    return r;
}
__device__ __forceinline__ float add_rn(float a, float b) {
    float r = a + b;
    asm volatile("" : "+v"(r));
    return r;
}

// fp32 -> bf16 round-to-nearest-even
__device__ __forceinline__ unsigned short f2bf(float x) {
    unsigned u = __float_as_uint(x);
    return (unsigned short)((u + 0x7fffu + ((u >> 16) & 1u)) >> 16);
}

// monotone pack: float score -> order-preserving u32, | code in low bits
__device__ __forceinline__ u64 packm(float s, int code) {
    unsigned b = __float_as_uint(s);
    unsigned mm = ((unsigned)((int)b >> 31)) | 0x80000000u;
    return ((u64)(b ^ mm) << 32) | (unsigned)code;
}

// async global->LDS, 16 B per lane; LDS dest = wave-uniform base + lane*16
__device__ __forceinline__ void gld16(const void* g, void* lds) {
    __builtin_amdgcn_global_load_lds(
        (const __attribute__((address_space(1))) unsigned int*)g,
        (__attribute__((address_space(3))) unsigned int*)lds, 16, 0, 0);
}

// ---------------- zprep: numpy-exact zsq + bf16 transpose-convert ----------------
// Block: 64 positions. Thread (hw = t&63, q = t>>6): 4 numpy chains of 16.
// Chain j of half h: elements d = h*128 + j + 8i (i sequential) — verified tree.
__global__ __launch_bounds__(256) void zprep(const float* __restrict__ z,
                                             float* __restrict__ zsq,
                                             unsigned short* __restrict__ zb16) {
    __shared__ float part[4][64];
    __shared__ unsigned short Lb[256 * 65];   // [d][hw], stride 65 (bank-spread)

    const int t  = threadIdx.x;
    const int hw = t & 63;
    const int q  = t >> 6;
    const int m0 = blockIdx.x * 64;
    const int h  = q >> 1;
    const int cb = (q & 1) * 4;
    const float* zimg = z + (m0 >> 10) * (DDIM * 1024) + (m0 & 1023) + hw;

    float v[4][16];
#pragma unroll
    for (int c = 0; c < 4; ++c)
#pragma unroll
        for (int i = 0; i < 16; ++i)
            v[c][i] = zimg[(h * 128 + cb + c + 8 * i) * 1024];

    float r[4];
#pragma unroll
    for (int c = 0; c < 4; ++c) {
        r[c] = sqr_rn(v[c][0]);
#pragma unroll
        for (int i = 1; i < 16; ++i) r[c] = add_rn(r[c], sqr_rn(v[c][i]));
    }
    // in-thread: (r0+r1)+(r2+r3) of this chain quartet (numpy tree left/right)
    part[q][hw] = add_rn(add_rn(r[0], r[1]), add_rn(r[2], r[3]));

#pragma unroll
    for (int c = 0; c < 4; ++c)
#pragma unroll
        for (int i = 0; i < 16; ++i) {
            const int d = h * 128 + cb + c + 8 * i;
            Lb[d * 65 + hw] = f2bf(v[c][i]);
        }
    __syncthreads();
    if (t < 64)
        zsq[m0 + t] = add_rn(add_rn(part[0][t], part[1][t]),
                             add_rn(part[2][t], part[3][t]));
    // write zb16 rows coalesced: chunk c -> row = c>>5, k8 = c&31
#pragma unroll
    for (int j = 0; j < 8; ++j) {
        const int c = t + j * 256;
        const int row = c >> 5, k8 = c & 31;
        bf16x8 o;
#pragma unroll
        for (int e = 0; e < 8; ++e) o[e] = (short)Lb[(k8 * 8 + e) * 65 + row];
        *(bf16x8*)&zb16[(m0 + row) * DDIM + k8 * 8] = o;
    }
}

// ---------------- wprep: numpy-exact wsq butterfly + bf16 convert ----------------
__global__ __launch_bounds__(256) void wprep(const float* __restrict__ W,
                                             float* __restrict__ wsq,
                                             unsigned short* __restrict__ wb16) {
    const int t   = threadIdx.x;
    const int row = blockIdx.x * 16 + (t >> 4);
    const int j   = t & 15;
    const float* base = W + row * DDIM + (j & 7) + (j >> 3) * 128;
    float r = sqr_rn(base[0]);
#pragma unroll
    for (int i = 1; i < 16; ++i) r = add_rn(r, sqr_rn(base[i * 8]));
#pragma unroll
    for (int m = 1; m <= 8; m <<= 1) r = add_rn(r, __shfl_xor(r, m));
    if (j == 0) wsq[row] = r;

    const int e0 = blockIdx.x * 4096 + t * 16;
#pragma unroll
    for (int g = 0; g < 2; ++g) {
        const float4 f0 = *(const float4*)&W[e0 + g * 8];
        const float4 f1 = *(const float4*)&W[e0 + g * 8 + 4];
        bf16x8 o;
        o[0] = (short)f2bf(f0.x); o[1] = (short)f2bf(f0.y);
        o[2] = (short)f2bf(f0.z); o[3] = (short)f2bf(f0.w);
        o[4] = (short)f2bf(f1.x); o[5] = (short)f2bf(f1.y);
        o[6] = (short)f2bf(f1.z); o[7] = (short)f2bf(f1.w);
        *(bf16x8*)&wb16[e0 + g * 8] = o;
    }
}

// ---------------- bf16 MFMA GEMM + per-block top-2 filter ----------------
// Grid 1024: mblk = bid>>2 (128 pos), nblk = bid&3 (256 codes). 4 waves.
// LDS A: [kq][128 m] 16B units (8 KB); B: [kq][256 n] 16B units (16 KB).
// Frag reads are 256B-contiguous per 16-lane phase -> conflict-free.
__global__ __launch_bounds__(256) __attribute__((amdgpu_waves_per_eu(2, 2)))
void gemm_top2(const unsigned short* __restrict__ zb16,
               const unsigned short* __restrict__ wb16,
               const float* __restrict__ wsq, u64* __restrict__ cand) {
    __shared__ u64 redU[4096];              // 32 KB; staging aliases low 24 KB
    char* Ab = (char*)redU;
    char* Bb = (char*)redU + 8192;

    const int t    = threadIdx.x;
    const int w    = t >> 6;
    const int l    = t & 63;
    const int ln   = l & 15;
    const int q    = l >> 4;
    const int mw   = (w & 1) * 64;
    const int nw   = (w >> 1) * 128;
    const int mblk = blockIdx.x >> 2;
    const int nblk = blockIdx.x & 3;
    const int m0   = mblk * 128;
    const int n0   = nblk * 256;

    // staging lane mapping: A slot s=i*256+w*64+l -> kq=s>>7, m=s&127
    //                       B slot s=i*256+w*64+l -> kq=i,    n=s&255
    const int am  = (w & 1) * 64 + l;
    const int akq = w >> 1;
    const char* gA0 = (const char*)(zb16 + (m0 + am) * DDIM) + akq * 16;
    const char* gB  = (const char*)(wb16 + (n0 + w * 64 + l) * DDIM);
    char* lA = Ab + w * 1024;
    char* lB = Bb + w * 1024;

    f32x4 acc[4][8];
#pragma unroll
    for (int a = 0; a < 4; ++a)
#pragma unroll
        for (int b = 0; b < 8; ++b) acc[a][b] = (f32x4)(0.f);

#pragma unroll 1
    for (int kk = 0; kk < 8; ++kk) {
        const int ko = kk * 64;   // byte offset within 512-B bf16 row
        gld16(gA0 + ko,      lA);            // kq = akq
        gld16(gA0 + ko + 32, lA + 4096);     // kq = akq + 2
        gld16(gB + ko,       lB);            // kq = 0
        gld16(gB + ko + 16,  lB + 4096);     // kq = 1
        gld16(gB + ko + 32,  lB + 8192);     // kq = 2
        gld16(gB + ko + 48,  lB + 12288);    // kq = 3
        __syncthreads();
        bf16x8 afr[4];
#pragma unroll
        for (int mf = 0; mf < 4; ++mf)
            afr[mf] = *(const bf16x8*)(Ab + q * 2048 + (mw + mf * 16 + ln) * 16);
#pragma unroll
        for (int nf = 0; nf < 8; ++nf) {
            const bf16x8 bfr = *(const bf16x8*)(Bb + q * 4096 + (nw + nf * 16 + ln) * 16);
#pragma unroll
            for (int mf = 0; mf < 4; ++mf)
                acc[mf][nf] = __builtin_amdgcn_mfma_f32_16x16x32_bf16(
                    afr[mf], bfr, acc[mf][nf], 0, 0, 0);
        }
        __syncthreads();
    }

    // ---- epilogue: approx score = wsq - 2*acc, per-row top-2 (round-4 verified) ----
    float wq[8];
#pragma unroll
    for (int nf = 0; nf < 8; ++nf) wq[nf] = wsq[n0 + nw + nf * 16 + ln];

#pragma unroll
    for (int mf = 0; mf < 4; ++mf) {
#pragma unroll
        for (int reg = 0; reg < 4; ++reg) {
            const int row = mw + mf * 16 + q * 4 + reg;
            float s0 = 1e30f, s1 = 1e30f;
            int   i0 = 0,     i1 = 0;
#pragma unroll
            for (int nf = 0; nf < 8; ++nf) {
                const float s  = fmaf(-2.f, acc[mf][nf][reg], wq[nf]);
                const int   cc = n0 + nw + nf * 16 + ln;
                if (s < s0)      { s1 = s0; i1 = i0; s0 = s; i0 = cc; }
                else if (s < s1) { s1 = s; i1 = cc; }
            }
            u64 p0 = packm(s0, i0), p1 = packm(s1, i1);
            const u64 o0 = __shfl_xor(p0, 1);
            const u64 o1 = __shfl_xor(p1, 1);
            const u64 c0 = (p0 < o0) ? p0 : o0;
            const u64 hi = (p0 < o0) ? o0 : p0;
            const u64 lo = (p1 < o1) ? p1 : o1;
            const u64 c1 = (hi < lo) ? hi : lo;
            if ((ln & 1) == 0) {
                u64* slot = &redU[row * 32 + (w >> 1) * 16 + (ln >> 1) * 2];
                slot[0] = c0;
                slot[1] = c1;
            }
        }
    }
    __syncthreads();
    {
        const int r2 = t >> 1, half = t & 1;
        u64 c0 = ~0ull, c1 = ~0ull;
#pragma unroll
        for (int j = 0; j < 16; ++j) {
            const u64 v = redU[r2 * 32 + half * 16 + j];
            if (v < c0)      { c1 = c0; c0 = v; }
            else if (v < c1) { c1 = v; }
        }
        __syncthreads();
        redU[r2 * 4 + half * 2]     = c0;
        redU[r2 * 4 + half * 2 + 1] = c1;
    }
    __syncthreads();
    if (t < 128) {
        const u64 a = redU[t * 4], b = redU[t * 4 + 1];
        const u64 c = redU[t * 4 + 2], d = redU[t * 4 + 3];
        const u64 m1 = (a < c) ? a : c;
        const u64 hi = (a < c) ? c : a;
        const u64 lo = (b < d) ? b : d;
        const u64 m2 = (hi < lo) ? hi : lo;
        u64* o = &cand[(u64)(m0 + t) * 8 + nblk * 2];
        o[0] = m1;
        o[1] = m2;
    }
}

// ---------------- exact numpy-bit rescore, z staged to LDS ----------------
#define ZS 260   // floats per LDS row: 1040 B (16B-aligned, bank-spread)
__global__ __launch_bounds__(256) void rescore(const float* __restrict__ z,
                                               const float* __restrict__ W,
                                               const float* __restrict__ zsq,
                                               const float* __restrict__ wsq,
                                               const u64* __restrict__ cand,
                                               int* __restrict__ out) {
    __shared__ float Zs[32 * ZS];   // 33.3 KB, [p][d]
    const int t  = threadIdx.x;
    const int m0 = blockIdx.x * 32;
    const float* zimg = z + (m0 >> 10) * (DDIM * 1024) + (m0 & 1023);
    // stage 32 pos x 256 d, coalesced float4 reads, transposed scalar stores
#pragma unroll
    for (int j = 0; j < 8; ++j) {
        const int f4 = t + j * 256;
        const int d = f4 >> 3, p4 = f4 & 7;
        const float4 v = *(const float4*)&zimg[d * 1024 + p4 * 4];
        Zs[(p4 * 4 + 0) * ZS + d] = v.x;
        Zs[(p4 * 4 + 1) * ZS + d] = v.y;
        Zs[(p4 * 4 + 2) * ZS + d] = v.z;
        Zs[(p4 * 4 + 3) * ZS + d] = v.w;
    }
    __syncthreads();
    const int pl = t >> 3, slot = t & 7;
    const int p = m0 + pl;
    const int code = (int)(unsigned)(cand[(u64)p * 8 + slot] & 0xffffffffULL);
    const float* wr = W + code * DDIM;
    const float* zr = &Zs[pl * ZS];
    // sequential fma chain over d ascending — bit-identical to verified path
    float M = 0.f;
#pragma unroll 8
    for (int d4 = 0; d4 < 64; ++d4) {
        const float4 zv = *(const float4*)&zr[d4 * 4];
        const float4 wv = *(const float4*)&wr[d4 * 4];
        M = fmaf(zv.x, wv.x, M);
        M = fmaf(zv.y, wv.y, M);
        M = fmaf(zv.z, wv.z, M);
        M = fmaf(zv.w, wv.w, M);
    }
    const float s = add_rn(fmaf(-2.f, M, zsq[p]), wsq[code]);
    u64 v = ((u64)__float_as_uint(s) << 32) | (unsigned)code;
#pragma unroll
    for (int m = 1; m <= 4; m <<= 1) {
        const u64 o = __shfl_xor(v, m);
        if (o < v) v = o;
    }
    if (slot == 0) out[p] = (int)(unsigned)(v & 0xffffffffULL);
}

extern "C" void kernel_launch(void* const* d_in, const int* in_sizes, int n_in,
                              void* d_out, int out_size, void* d_ws, size_t ws_size,
                              hipStream_t stream) {
    const float* z = (const float*)d_in[0];   // [32, 256, 32, 32] NCHW
    const float* W = (const float*)d_in[1];   // [1024, 256]
    int* out = (int*)d_out;                   // [32768] int32 indices

    char* ws = (char*)d_ws;
    float*          zsq  = (float*)ws;                       // 128 KB @ 0
    float*          wsq  = (float*)(ws + 131072);            //   4 KB
    u64*            cand = (u64*)(ws + 135168);              //   2 MB
    unsigned short* zb16 = (unsigned short*)(ws + 2232320);  //  16 MB
    unsigned short* wb16 = (unsigned short*)(ws + 19009536); // 512 KB

    wprep<<<KCODES / 16, 256, 0, stream>>>(W, wsq, wb16);
    zprep<<<NPOS / 64, 256, 0, stream>>>(z, zsq, zb16);
    gemm_top2<<<(NPOS / 128) * 4, 256, 0, stream>>>(zb16, wb16, wsq, cand);
    rescore<<<NPOS / 32, 256, 0, stream>>>(z, W, zsq, wsq, cand, out);
}

// Round 7
// 149.014 us; speedup vs baseline: 2.5136x; 1.0964x over previous
//
#include <hip/hip_runtime.h>

#define NPOS 32768   // 32 * 32 * 32 positions
#define DDIM 256
#define KCODES 1024

typedef __attribute__((ext_vector_type(8))) short bf16x8;
typedef __attribute__((ext_vector_type(4))) float f32x4;
typedef unsigned long long u64;

// ---- fp32 ops with anti-contraction barriers (replicate numpy rounding) ----
__device__ __forceinline__ float sqr_rn(float x) {
    float r = x * x;
    asm volatile("" : "+v"(r));
    return r;
}
__device__ __forceinline__ float add_rn(float a, float b) {
    float r = a + b;
    asm volatile("" : "+v"(r));
    return r;
}

// fp32 -> bf16 round-to-nearest-even
__device__ __forceinline__ unsigned short f2bf(float x) {
    unsigned u = __float_as_uint(x);
    return (unsigned short)((u + 0x7fffu + ((u >> 16) & 1u)) >> 16);
}

// monotone pack: float score -> order-preserving u32, | code in low bits
__device__ __forceinline__ u64 packm(float s, int code) {
    unsigned b = __float_as_uint(s);
    unsigned mm = ((unsigned)((int)b >> 31)) | 0x80000000u;
    return ((u64)(b ^ mm) << 32) | (unsigned)code;
}

// async global->LDS: GLOBAL side is PER-LANE (lane i must pass base+i*16);
// LDS side is wave-uniform base + lane*16 (m104/m108).
__device__ __forceinline__ void gld16(const void* g, void* lds) {
    __builtin_amdgcn_global_load_lds(
        (const __attribute__((address_space(1))) unsigned int*)g,
        (__attribute__((address_space(3))) unsigned int*)lds, 16, 0, 0);
}

// ---------------- zconv: fp32 NCHW -> bf16 tiled [mtile][kk][kq][m] ----------------
// Block = (img, 8-d chunk): reads 8 x 1024 floats coalesced, LDS transpose,
// writes 1 KB-contiguous bf16x8 runs in the exact gemm LDS order.
__global__ __launch_bounds__(256) void zconv(const float* __restrict__ z,
                                             unsigned short* __restrict__ zb16t) {
    __shared__ unsigned short Ls[8 * 1024];   // [e][hw] bf16, 16 KB
    const int t   = threadIdx.x;
    const int img = blockIdx.x >> 5;
    const int dc  = blockIdx.x & 31;          // d-chunk: d = dc*8 + e
    const int kk  = dc >> 2, kq = dc & 3;
    const float* zr = z + img * (DDIM * 1024) + dc * 8 * 1024;
#pragma unroll
    for (int e = 0; e < 8; ++e) {
        const float4 v = *(const float4*)&zr[e * 1024 + t * 4];
        unsigned short* o = &Ls[e * 1024 + t * 4];
        o[0] = f2bf(v.x); o[1] = f2bf(v.y); o[2] = f2bf(v.z); o[3] = f2bf(v.w);
    }
    __syncthreads();
#pragma unroll
    for (int j = 0; j < 4; ++j) {
        const int m = t + j * 256;            // position within image
        const int mtile = img * 8 + (m >> 7);
        bf16x8 o;
#pragma unroll
        for (int e = 0; e < 8; ++e) o[e] = (short)Ls[e * 1024 + m];
        *(bf16x8*)&zb16t[mtile * 32768 + kk * 4096 + kq * 1024 + (m & 127) * 8] = o;
    }
}

// ---------------- wprep: numpy-exact wsq butterfly + bf16 tiled convert ----------------
__global__ __launch_bounds__(256) void wprep(const float* __restrict__ W,
                                             float* __restrict__ wsq,
                                             unsigned short* __restrict__ wb16t) {
    const int t   = threadIdx.x;
    const int row = blockIdx.x * 16 + (t >> 4);
    const int j   = t & 15;
    const float* base = W + row * DDIM + (j & 7) + (j >> 3) * 128;
    float r = sqr_rn(base[0]);
#pragma unroll
    for (int i = 1; i < 16; ++i) r = add_rn(r, sqr_rn(base[i * 8]));
#pragma unroll
    for (int m = 1; m <= 8; m <<= 1) r = add_rn(r, __shfl_xor(r, m));
    if (j == 0) wsq[row] = r;

    // convert 16 rows to tiled [ntile][kk][kq][n] layout
#pragma unroll
    for (int jj = 0; jj < 2; ++jj) {
        const int u  = t + jj * 256;          // 512 units = 16 rows x 32 k8
        const int n  = blockIdx.x * 16 + (u >> 5);
        const int k8 = u & 31;
        const float4 f0 = *(const float4*)&W[n * DDIM + k8 * 8];
        const float4 f1 = *(const float4*)&W[n * DDIM + k8 * 8 + 4];
        bf16x8 o;
        o[0] = (short)f2bf(f0.x); o[1] = (short)f2bf(f0.y);
        o[2] = (short)f2bf(f0.z); o[3] = (short)f2bf(f0.w);
        o[4] = (short)f2bf(f1.x); o[5] = (short)f2bf(f1.y);
        o[6] = (short)f2bf(f1.z); o[7] = (short)f2bf(f1.w);
        const int kk = k8 >> 2, kq = k8 & 3;
        *(bf16x8*)&wb16t[(n >> 8) * 65536 + kk * 8192 + kq * 2048 + (n & 255) * 8] = o;
    }
}

// ---------------- bf16 MFMA GEMM + per-block top-2 filter ----------------
// Grid 1024: mblk = bid>>2 (128 pos), nblk = bid&3 (256 codes). 4 waves.
// Tiled inputs: every gld16 stages a contiguous 1 KB wave-burst.
__global__ __launch_bounds__(256) __attribute__((amdgpu_waves_per_eu(2, 2)))
void gemm_top2(const unsigned short* __restrict__ zb16t,
               const unsigned short* __restrict__ wb16t,
               const float* __restrict__ wsq, u64* __restrict__ cand) {
    __shared__ u64 redU[4096];              // 32 KB; staging aliases low 24 KB
    char* Ab = (char*)redU;                 // [kq][m] 16B units, 8 KB
    char* Bb = (char*)redU + 8192;          // [kq][n] 16B units, 16 KB

    const int t    = threadIdx.x;
    const int w    = t >> 6;
    const int l    = t & 63;
    const int lg   = l * 16;                // per-lane global byte offset
    const int ln   = l & 15;
    const int q    = l >> 4;
    const int mw   = (w & 1) * 64;
    const int nw   = (w >> 1) * 128;
    const int mblk = blockIdx.x >> 2;
    const int nblk = blockIdx.x & 3;
    const int m0   = mblk * 128;
    const int n0   = nblk * 256;

    const char* Az = (const char*)zb16t + (size_t)mblk * 65536;
    const char* Bz = (const char*)wb16t + (size_t)nblk * 131072;

    f32x4 acc[4][8];
#pragma unroll
    for (int a = 0; a < 4; ++a)
#pragma unroll
        for (int b = 0; b < 8; ++b) acc[a][b] = (f32x4)(0.f);

#pragma unroll 1
    for (int kk = 0; kk < 8; ++kk) {
        const char* a = Az + kk * 8192 + lg;
        const char* b = Bz + kk * 16384 + lg;
        gld16(a + w * 1024,        Ab + w * 1024);
        gld16(a + (4 + w) * 1024,  Ab + (4 + w) * 1024);
        gld16(b + w * 1024,        Bb + w * 1024);
        gld16(b + (4 + w) * 1024,  Bb + (4 + w) * 1024);
        gld16(b + (8 + w) * 1024,  Bb + (8 + w) * 1024);
        gld16(b + (12 + w) * 1024, Bb + (12 + w) * 1024);
        __syncthreads();
        bf16x8 afr[4];
#pragma unroll
        for (int mf = 0; mf < 4; ++mf)
            afr[mf] = *(const bf16x8*)(Ab + q * 2048 + (mw + mf * 16 + ln) * 16);
#pragma unroll
        for (int nf = 0; nf < 8; ++nf) {
            const bf16x8 bfr = *(const bf16x8*)(Bb + q * 4096 + (nw + nf * 16 + ln) * 16);
#pragma unroll
            for (int mf = 0; mf < 4; ++mf)
                acc[mf][nf] = __builtin_amdgcn_mfma_f32_16x16x32_bf16(
                    afr[mf], bfr, acc[mf][nf], 0, 0, 0);
        }
        __syncthreads();
    }

    // ---- epilogue: approx score = wsq - 2*acc, per-row top-2 (verified r4/r5) ----
    float wq[8];
#pragma unroll
    for (int nf = 0; nf < 8; ++nf) wq[nf] = wsq[n0 + nw + nf * 16 + ln];

#pragma unroll
    for (int mf = 0; mf < 4; ++mf) {
#pragma unroll
        for (int reg = 0; reg < 4; ++reg) {
            const int row = mw + mf * 16 + q * 4 + reg;
            float s0 = 1e30f, s1 = 1e30f;
            int   i0 = 0,     i1 = 0;
#pragma unroll
            for (int nf = 0; nf < 8; ++nf) {
                const float s  = fmaf(-2.f, acc[mf][nf][reg], wq[nf]);
                const int   cc = n0 + nw + nf * 16 + ln;
                if (s < s0)      { s1 = s0; i1 = i0; s0 = s; i0 = cc; }
                else if (s < s1) { s1 = s; i1 = cc; }
            }
            u64 p0 = packm(s0, i0), p1 = packm(s1, i1);
            const u64 o0 = __shfl_xor(p0, 1);
            const u64 o1 = __shfl_xor(p1, 1);
            const u64 c0 = (p0 < o0) ? p0 : o0;
            const u64 hi = (p0 < o0) ? o0 : p0;
            const u64 lo = (p1 < o1) ? p1 : o1;
            const u64 c1 = (hi < lo) ? hi : lo;
            if ((ln & 1) == 0) {
                u64* slot = &redU[row * 32 + (w >> 1) * 16 + (ln >> 1) * 2];
                slot[0] = c0;
                slot[1] = c1;
            }
        }
    }
    __syncthreads();
    {
        const int r2 = t >> 1, half = t & 1;
        u64 c0 = ~0ull, c1 = ~0ull;
#pragma unroll
        for (int j = 0; j < 16; ++j) {
            const u64 v = redU[r2 * 32 + half * 16 + j];
            if (v < c0)      { c1 = c0; c0 = v; }
            else if (v < c1) { c1 = v; }
        }
        __syncthreads();
        redU[r2 * 4 + half * 2]     = c0;
        redU[r2 * 4 + half * 2 + 1] = c1;
    }
    __syncthreads();
    if (t < 128) {
        const u64 a = redU[t * 4], b = redU[t * 4 + 1];
        const u64 c = redU[t * 4 + 2], d = redU[t * 4 + 3];
        const u64 m1 = (a < c) ? a : c;
        const u64 hi = (a < c) ? c : a;
        const u64 lo = (b < d) ? b : d;
        const u64 m2 = (hi < lo) ? hi : lo;
        u64* o = &cand[(u64)(m0 + t) * 8 + nblk * 2];
        o[0] = m1;
        o[1] = m2;
    }
}

// ---------------- exact numpy-bit rescore + in-kernel numpy-exact zsq ----------------
#define ZS 260   // floats per LDS row (bank-spread)
__global__ __launch_bounds__(256) void rescore(const float* __restrict__ z,
                                               const float* __restrict__ W,
                                               const float* __restrict__ wsq,
                                               const u64* __restrict__ cand,
                                               int* __restrict__ out) {
    __shared__ float Zs[32 * ZS];   // 33.3 KB, [p][d] fp32
    const int t  = threadIdx.x;
    const int m0 = blockIdx.x * 32;
    const float* zimg = z + (m0 >> 10) * (DDIM * 1024) + (m0 & 1023);
#pragma unroll
    for (int j = 0; j < 8; ++j) {
        const int f4 = t + j * 256;
        const int d = f4 >> 3, p4 = f4 & 7;
        const float4 v = *(const float4*)&zimg[d * 1024 + p4 * 4];
        Zs[(p4 * 4 + 0) * ZS + d] = v.x;
        Zs[(p4 * 4 + 1) * ZS + d] = v.y;
        Zs[(p4 * 4 + 2) * ZS + d] = v.z;
        Zs[(p4 * 4 + 3) * ZS + d] = v.w;
    }
    __syncthreads();
    const int pl = t >> 3, slot = t & 7;
    const int p = m0 + pl;
    const float* zr = &Zs[pl * ZS];

    // numpy-exact zsq: slot s owns chain s of each 128-half (sequential 16);
    // xor1/xor2/xor4 butterfly = ((r0+r1)+(r2+r3))+((r4+r5)+(r6+r7)) per half
    // (IEEE add commutative -> bit-identical across lanes); halves joined last.
    float h0 = sqr_rn(zr[slot]);
    float h1 = sqr_rn(zr[128 + slot]);
#pragma unroll
    for (int i = 1; i < 16; ++i) {
        h0 = add_rn(h0, sqr_rn(zr[slot + 8 * i]));
        h1 = add_rn(h1, sqr_rn(zr[128 + slot + 8 * i]));
    }
#pragma unroll
    for (int m = 1; m <= 4; m <<= 1) {
        h0 = add_rn(h0, __shfl_xor(h0, m));
        h1 = add_rn(h1, __shfl_xor(h1, m));
    }
    const float zq = add_rn(h0, h1);

    const int code = (int)(unsigned)(cand[(u64)p * 8 + slot] & 0xffffffffULL);
    const float* wr = W + code * DDIM;
    // sequential fma chain over d ascending — bit-identical to verified path
    float M = 0.f;
#pragma unroll 8
    for (int d4 = 0; d4 < 64; ++d4) {
        const float4 zv = *(const float4*)&zr[d4 * 4];
        const float4 wv = *(const float4*)&wr[d4 * 4];
        M = fmaf(zv.x, wv.x, M);
        M = fmaf(zv.y, wv.y, M);
        M = fmaf(zv.z, wv.z, M);
        M = fmaf(zv.w, wv.w, M);
    }
    const float s = add_rn(fmaf(-2.f, M, zq), wsq[code]);
    u64 v = ((u64)__float_as_uint(s) << 32) | (unsigned)code;
#pragma unroll
    for (int m = 1; m <= 4; m <<= 1) {
        const u64 o = __shfl_xor(v, m);
        if (o < v) v = o;
    }
    if (slot == 0) out[p] = (int)(unsigned)(v & 0xffffffffULL);
}

extern "C" void kernel_launch(void* const* d_in, const int* in_sizes, int n_in,
                              void* d_out, int out_size, void* d_ws, size_t ws_size,
                              hipStream_t stream) {
    const float* z = (const float*)d_in[0];   // [32, 256, 32, 32] NCHW
    const float* W = (const float*)d_in[1];   // [1024, 256]
    int* out = (int*)d_out;                   // [32768] int32 indices

    char* ws = (char*)d_ws;
    float*          wsq   = (float*)ws;                        //   4 KB @ 0
    u64*            cand  = (u64*)(ws + 4096);                 //   2 MB
    unsigned short* zb16t = (unsigned short*)(ws + 2101248);   //  16 MB
    unsigned short* wb16t = (unsigned short*)(ws + 18878464);  // 512 KB

    wprep<<<KCODES / 16, 256, 0, stream>>>(W, wsq, wb16t);
    zconv<<<32 * 32, 256, 0, stream>>>(z, zb16t);
    gemm_top2<<<(NPOS / 128) * 4, 256, 0, stream>>>(zb16t, wb16t, wsq, cand);
    rescore<<<NPOS / 32, 256, 0, stream>>>(z, W, wsq, cand, out);
}